// Round 1
// baseline (1111.695 us; speedup 1.0000x reference)
//
#include <hip/hip_runtime.h>
#include <math.h>

// Problem constants
#define S       2048
#define D       2048
#define EQ      2048   // N_Q_HEADS * HEAD_DIM
#define EK      512    // N_KV_HEADS * HEAD_DIM
#define ETOT    2560   // EQ + EK
#define NH      32
#define NKV     8
#define HD      64
#define KLEN    1024   // max(S*0.5, 2)

// Workspace layout (byte offsets)
#define OFF_COS   ((size_t)0)                    // [S][32] f32 = 256KB
#define OFF_SIN   ((size_t)(256u << 10))         // 256KB
#define OFF_QK    ((size_t)(1u << 20))           // [S][ETOT] f32 = 20MB
#define OFF_KT    ((size_t)(22u << 20))          // [NKV][64][S] f32 = 4MB
#define OFF_PART  ((size_t)(26u << 20))          // [1024][S] f32 = 8MB
#define OFF_ACCP  ((size_t)(34u << 20))          // [32][S] f64 = 512KB

// ---------------------------------------------------------------------------
// 1) cos/sin tables. Computed in fp64 (fp32 arg to cos at pos~2047 has ~1e-4
//    error, which is j-correlated and would destabilize the topk boundary).
__global__ void trig_kernel(float* __restrict__ cosT, float* __restrict__ sinT) {
  int idx = blockIdx.x * blockDim.x + threadIdx.x;  // S*32 = 65536
  int s = idx >> 5, i = idx & 31;
  double invf = 1.0 / pow(10000.0, (double)i / 32.0);
  double ang = (double)s * invf;
  cosT[idx] = (float)cos(ang);
  sinT[idx] = (float)sin(ang);
}

// ---------------------------------------------------------------------------
// 2) Fused gather + projection GEMM: C[s][e] = sum_d embed[ids[s]][d]*W[e][d]
//    C = [S][ETOT]; cols < EQ from Wq, cols >= EQ from Wk.
//    Tiles: BM=128 rows x BN=64 cols x BK=16, 256 threads, 4x8 micro-tile.
__global__ __launch_bounds__(256) void proj_gemm(
    const int* __restrict__ ids, const float* __restrict__ embed,
    const float* __restrict__ Wq, const float* __restrict__ Wk,
    float* __restrict__ C) {
  __shared__ float As[16][128];
  __shared__ float Bs[16][64];
  __shared__ int rowid[128];
  const int t = threadIdx.x;
  const int col0 = blockIdx.x * 64;    // 0..2560-64
  const int row0 = blockIdx.y * 128;   // 0..2048-128
  const float* Wbase = (col0 < EQ) ? (Wq + (size_t)col0 * D)
                                   : (Wk + (size_t)(col0 - EQ) * D);
  if (t < 128) rowid[t] = ids[row0 + t];

  const int tn0 = (t & 7) * 8;     // 8 cols
  const int tm0 = (t >> 3) * 4;    // 4 rows
  float acc[4][8];
#pragma unroll
  for (int i = 0; i < 4; ++i)
#pragma unroll
    for (int j = 0; j < 8; ++j) acc[i][j] = 0.f;

  for (int k0 = 0; k0 < D; k0 += 16) {
    __syncthreads();
    // A tile 128x16 (gathered rows), transposed into As[k][m]
#pragma unroll
    for (int it = 0; it < 2; ++it) {
      int m = (t >> 2) + it * 64;
      int kq = (t & 3) * 4;
      const float4 v = *(const float4*)(embed + (size_t)rowid[m] * D + k0 + kq);
      As[kq + 0][m] = v.x; As[kq + 1][m] = v.y;
      As[kq + 2][m] = v.z; As[kq + 3][m] = v.w;
    }
    // B tile 64x16 into Bs[k][n]
    {
      int n = (t >> 2);
      int kq = (t & 3) * 4;
      const float4 v = *(const float4*)(Wbase + (size_t)n * D + k0 + kq);
      Bs[kq + 0][n] = v.x; Bs[kq + 1][n] = v.y;
      Bs[kq + 2][n] = v.z; Bs[kq + 3][n] = v.w;
    }
    __syncthreads();
#pragma unroll
    for (int kk = 0; kk < 16; ++kk) {
      float a[4], b[8];
#pragma unroll
      for (int i = 0; i < 4; ++i) a[i] = As[kk][tm0 + i];
#pragma unroll
      for (int j = 0; j < 8; ++j) b[j] = Bs[kk][tn0 + j];
#pragma unroll
      for (int i = 0; i < 4; ++i)
#pragma unroll
        for (int j = 0; j < 8; ++j) acc[i][j] = fmaf(a[i], b[j], acc[i][j]);
    }
  }
#pragma unroll
  for (int i = 0; i < 4; ++i) {
    float* dst = C + (size_t)(row0 + tm0 + i) * ETOT + col0 + tn0;
    *(float4*)dst       = make_float4(acc[i][0], acc[i][1], acc[i][2], acc[i][3]);
    *(float4*)(dst + 4) = make_float4(acc[i][4], acc[i][5], acc[i][6], acc[i][7]);
  }
}

// ---------------------------------------------------------------------------
// 3) RoPE on q, in place. One thread owns the (i, i+32) pair -> no race.
__global__ void rope_q_kernel(float* __restrict__ qk,
                              const float* __restrict__ cosT,
                              const float* __restrict__ sinT) {
  int idx = blockIdx.x * blockDim.x + threadIdx.x;  // S * NH * 32 = 2097152
  int s = idx >> 10;
  int rem = idx & 1023;
  int h = rem >> 5, i = rem & 31;
  float c = cosT[(s << 5) + i], sn = sinT[(s << 5) + i];
  float* p = qk + (size_t)s * ETOT + h * HD + i;
  float x1 = p[0], x2 = p[32];
  p[0]  = fmaf(x1, c, -x2 * sn);
  p[32] = fmaf(x2, c,  x1 * sn);
}

// 4) RoPE on k, writing transposed kT[kv][d][s] for coalesced attn loads.
__global__ void rope_k_kernel(const float* __restrict__ qk,
                              float* __restrict__ kT,
                              const float* __restrict__ cosT,
                              const float* __restrict__ sinT) {
  int idx = blockIdx.x * blockDim.x + threadIdx.x;  // S * NKV * 32 = 524288
  int s = idx & (S - 1);
  int rem = idx >> 11;       // 0..255
  int kv = rem >> 5, i = rem & 31;
  float c = cosT[(s << 5) + i], sn = sinT[(s << 5) + i];
  const float* p = qk + (size_t)s * ETOT + EQ + kv * HD + i;
  float x1 = p[0], x2 = p[32];
  kT[(size_t)(kv * HD + i) * S + s]      = fmaf(x1, c, -x2 * sn);
  kT[(size_t)(kv * HD + i + 32) * S + s] = fmaf(x2, c,  x1 * sn);
}

// ---------------------------------------------------------------------------
// 5) Attention: per (head, superblock of 64 rows): scores -> exp -> row-sum
//    (wave shuffle reduce, deterministic) -> accumulate column sums of
//    softmax into registers; one fp32 partial row per block.
__global__ __launch_bounds__(256) void attn_kernel(
    const float* __restrict__ qk, const float* __restrict__ kT,
    float* __restrict__ part) {
  const int h = blockIdx.x;    // 0..31
  const int sb = blockIdx.y;   // 0..31
  const int t = threadIdx.x;
  const float* kTh = kT + (size_t)(h >> 2) * HD * S;
  __shared__ float qlds[8][64];
  __shared__ float wred[4][8];
  float colacc[8];
#pragma unroll
  for (int u = 0; u < 8; ++u) colacc[u] = 0.f;

  for (int ch = 0; ch < 8; ++ch) {
    const int row0 = sb * 64 + ch * 8;
    __syncthreads();
    for (int e = t; e < 512; e += 256) {
      int r = e >> 6, d = e & 63;
      qlds[r][d] = qk[(size_t)(row0 + r) * ETOT + h * HD + d];
    }
    __syncthreads();
    float acc[8][8];
#pragma unroll
    for (int r = 0; r < 8; ++r)
#pragma unroll
      for (int u = 0; u < 8; ++u) acc[r][u] = 0.f;
    for (int d = 0; d < HD; ++d) {
      float kv8[8];
#pragma unroll
      for (int u = 0; u < 8; ++u) kv8[u] = kTh[(size_t)d * S + t + 256 * u];
#pragma unroll
      for (int r = 0; r < 8; ++r) {
        const float qd = qlds[r][d];
#pragma unroll
        for (int u = 0; u < 8; ++u) acc[r][u] = fmaf(qd, kv8[u], acc[r][u]);
      }
    }
    // exp + per-row sums (scores are tiny, |s|<~0.02: no max-sub needed)
    float p[8];
#pragma unroll
    for (int r = 0; r < 8; ++r) {
      p[r] = 0.f;
#pragma unroll
      for (int u = 0; u < 8; ++u) {
        acc[r][u] = expf(acc[r][u]);
        p[r] += acc[r][u];
      }
    }
#pragma unroll
    for (int off = 32; off > 0; off >>= 1)
#pragma unroll
      for (int r = 0; r < 8; ++r) p[r] += __shfl_xor(p[r], off, 64);
    if ((t & 63) == 0) {
#pragma unroll
      for (int r = 0; r < 8; ++r) wred[t >> 6][r] = p[r];
    }
    __syncthreads();
#pragma unroll
    for (int r = 0; r < 8; ++r) {
      const float Z = wred[0][r] + wred[1][r] + wred[2][r] + wred[3][r];
      const float inv = 1.f / Z;
#pragma unroll
      for (int u = 0; u < 8; ++u) colacc[u] = fmaf(acc[r][u], inv, colacc[u]);
    }
  }
  const int b = h * 32 + sb;
#pragma unroll
  for (int u = 0; u < 8; ++u)
    part[(size_t)b * S + t + 256 * u] = colacc[u];
}

// ---------------------------------------------------------------------------
// 6) fp64 reduction of the 1024 fp32 partials, stage 1 (32 groups of 32).
__global__ void reduce_kernel(const float* __restrict__ part,
                              double* __restrict__ accp) {
  int j = blockIdx.x * 256 + threadIdx.x;  // 0..2047
  int g = blockIdx.y;                      // 0..31
  double s = 0.0;
  for (int b = g * 32; b < g * 32 + 32; ++b) s += (double)part[(size_t)b * S + j];
  accp[(size_t)g * S + j] = s;
}

// ---------------------------------------------------------------------------
// 7) Final fp64 sum + exact top-k (tie-break: lower index, matching
//    lax.top_k) + index-sort via rank counting + output write.
__global__ __launch_bounds__(1024) void topk_kernel(
    const double* __restrict__ accp, const int* __restrict__ ids,
    int* __restrict__ out) {
  __shared__ double vals[S];   // 16KB
  __shared__ int flags[S];     // 8KB
  const int t = threadIdx.x;
  for (int j = t; j < S; j += 1024) {
    double s = 0.0;
    for (int g = 0; g < 32; ++g) s += accp[(size_t)g * S + j];
    vals[j] = s;
  }
  __syncthreads();
  for (int j = t; j < S; j += 1024) {
    const double v = vals[j];
    int rank = 0;
    for (int j2 = 0; j2 < S; ++j2) {
      double v2 = vals[j2];
      rank += (v2 > v) || (v2 == v && j2 < j);
    }
    flags[j] = (rank < KLEN) ? 1 : 0;
  }
  __syncthreads();
  for (int j = t; j < S; j += 1024) {
    if (flags[j]) {
      int pos = 0;
      for (int j2 = 0; j2 < j; ++j2) pos += flags[j2];
      out[pos] = ids[j];            // pruned tokens [0..1024]
      out[KLEN + 1 + pos] = j;      // indices [1025..2049]
    }
  }
  if (t == 0) {
    out[KLEN] = ids[S - 1];
    out[KLEN + 1 + KLEN] = S - 1;
  }
}

// ---------------------------------------------------------------------------
extern "C" void kernel_launch(void* const* d_in, const int* in_sizes, int n_in,
                              void* d_out, int out_size, void* d_ws, size_t ws_size,
                              hipStream_t stream) {
  const int* ids = (const int*)d_in[0];
  const float* embed = (const float*)d_in[1];
  const float* Wq = (const float*)d_in[2];
  const float* Wk = (const float*)d_in[3];
  int* out = (int*)d_out;
  char* ws = (char*)d_ws;
  float* cosT = (float*)(ws + OFF_COS);
  float* sinT = (float*)(ws + OFF_SIN);
  float* qk   = (float*)(ws + OFF_QK);
  float* kT   = (float*)(ws + OFF_KT);
  float* part = (float*)(ws + OFF_PART);
  double* accp = (double*)(ws + OFF_ACCP);

  trig_kernel<<<256, 256, 0, stream>>>(cosT, sinT);
  proj_gemm<<<dim3(ETOT / 64, S / 128), 256, 0, stream>>>(ids, embed, Wq, Wk, qk);
  rope_q_kernel<<<(S * NH * 32) / 256, 256, 0, stream>>>(qk, cosT, sinT);
  rope_k_kernel<<<(S * NKV * 32) / 256, 256, 0, stream>>>(qk, kT, cosT, sinT);
  attn_kernel<<<dim3(NH, 32), 256, 0, stream>>>(qk, kT, part);
  reduce_kernel<<<dim3(S / 256, 32), 256, 0, stream>>>(part, accp);
  topk_kernel<<<1, 1024, 0, stream>>>(accp, ids, out);
}

// Round 2
// 976.917 us; speedup vs baseline: 1.1380x; 1.1380x over previous
//
#include <hip/hip_runtime.h>
#include <math.h>

// Problem constants
#define S       2048
#define D       2048
#define EQ      2048   // N_Q_HEADS * HEAD_DIM
#define EK      512    // N_KV_HEADS * HEAD_DIM
#define ETOT    2560   // EQ + EK
#define NH      32
#define NKV     8
#define HD      64
#define KLEN    1024   // max(S*0.5, 2)

// Workspace layout (byte offsets)
#define OFF_COS   ((size_t)0)                    // [S][32] f32 = 256KB
#define OFF_SIN   ((size_t)(256u << 10))         // 256KB
#define OFF_QK    ((size_t)(1u << 20))           // [S][ETOT] f32 = 20MB
#define OFF_KT    ((size_t)(22u << 20))          // [NKV][64][S] f32 = 4MB
#define OFF_PART  ((size_t)(26u << 20))          // [1024][S] f32 = 8MB
#define OFF_VALS  ((size_t)(34u << 20))          // [S] f64 = 16KB
#define OFF_FLAGS ((size_t)((34u << 20) + (16u << 10)))  // [S] i32 = 8KB

// ---------------------------------------------------------------------------
// 1) cos/sin tables in fp64 (fp32 arg reduction at pos~2047 gives ~1e-4 error,
//    j-correlated -> would destabilize the topk boundary).
__global__ void trig_kernel(float* __restrict__ cosT, float* __restrict__ sinT) {
  int idx = blockIdx.x * blockDim.x + threadIdx.x;  // S*32 = 65536
  int s = idx >> 5, i = idx & 31;
  double invf = 1.0 / pow(10000.0, (double)i / 32.0);
  double ang = (double)s * invf;
  cosT[idx] = (float)cos(ang);
  sinT[idx] = (float)sin(ang);
}

// ---------------------------------------------------------------------------
// 2) Fused gather + projection GEMM: C[s][e] = sum_d embed[ids[s]][d]*W[e][d]
//    64x64 tile, BK=16, 256 threads, 4x4 microtile, ds_read_b128 LDS reads.
//    Per-element k-accumulation order identical to R1 (bit-stable numerics).
#define BM 64
#define BN 64
#define BK 16
__global__ __launch_bounds__(256) void proj_gemm(
    const int* __restrict__ ids, const float* __restrict__ embed,
    const float* __restrict__ Wq, const float* __restrict__ Wk,
    float* __restrict__ C) {
  __shared__ float As[BK][BM + 4];   // +4 pad: 16B-aligned rows, 2-way-max conflicts
  __shared__ float Bs[BK][BN + 4];
  __shared__ int rowid[BM];
  const int t = threadIdx.x;
  const int col0 = blockIdx.x * BN;    // 40 col blocks
  const int row0 = blockIdx.y * BM;    // 32 row blocks
  const float* Wbase = (col0 < EQ) ? (Wq + (size_t)col0 * D)
                                   : (Wk + (size_t)(col0 - EQ) * D);
  if (t < BM) rowid[t] = ids[row0 + t];
  __syncthreads();
  const int lm = t >> 2;          // 0..63: staged row
  const int lk = (t & 3) * 4;     // 0,4,8,12: k quad
  const float* Arow = embed + (size_t)rowid[lm] * D + lk;
  const float* Brow = Wbase + (size_t)lm * D + lk;
  const int tn0 = (t & 15) * 4;
  const int tm0 = (t >> 4) * 4;
  float acc[4][4];
#pragma unroll
  for (int i = 0; i < 4; ++i)
#pragma unroll
    for (int j = 0; j < 4; ++j) acc[i][j] = 0.f;

  float4 av = *(const float4*)(Arow);
  float4 bv = *(const float4*)(Brow);
  for (int k0 = 0; k0 < D; k0 += BK) {
    __syncthreads();
    As[lk + 0][lm] = av.x; As[lk + 1][lm] = av.y;
    As[lk + 2][lm] = av.z; As[lk + 3][lm] = av.w;
    Bs[lk + 0][lm] = bv.x; Bs[lk + 1][lm] = bv.y;
    Bs[lk + 2][lm] = bv.z; Bs[lk + 3][lm] = bv.w;
    __syncthreads();
    // prefetch next k-tile (wraps to 0 on last iter; values discarded)
    const int kn = (k0 + BK) & (D - 1);
    av = *(const float4*)(Arow + kn);
    bv = *(const float4*)(Brow + kn);
#pragma unroll
    for (int kk = 0; kk < BK; ++kk) {
      const float4 a = *(const float4*)&As[kk][tm0];
      const float4 b = *(const float4*)&Bs[kk][tn0];
      acc[0][0] = fmaf(a.x, b.x, acc[0][0]); acc[0][1] = fmaf(a.x, b.y, acc[0][1]);
      acc[0][2] = fmaf(a.x, b.z, acc[0][2]); acc[0][3] = fmaf(a.x, b.w, acc[0][3]);
      acc[1][0] = fmaf(a.y, b.x, acc[1][0]); acc[1][1] = fmaf(a.y, b.y, acc[1][1]);
      acc[1][2] = fmaf(a.y, b.z, acc[1][2]); acc[1][3] = fmaf(a.y, b.w, acc[1][3]);
      acc[2][0] = fmaf(a.z, b.x, acc[2][0]); acc[2][1] = fmaf(a.z, b.y, acc[2][1]);
      acc[2][2] = fmaf(a.z, b.z, acc[2][2]); acc[2][3] = fmaf(a.z, b.w, acc[2][3]);
      acc[3][0] = fmaf(a.w, b.x, acc[3][0]); acc[3][1] = fmaf(a.w, b.y, acc[3][1]);
      acc[3][2] = fmaf(a.w, b.z, acc[3][2]); acc[3][3] = fmaf(a.w, b.w, acc[3][3]);
    }
  }
#pragma unroll
  for (int i = 0; i < 4; ++i) {
    float* dst = C + (size_t)(row0 + tm0 + i) * ETOT + col0 + tn0;
    *(float4*)dst = make_float4(acc[i][0], acc[i][1], acc[i][2], acc[i][3]);
  }
}

// ---------------------------------------------------------------------------
// 3) RoPE on q, in place. One thread owns the (i, i+32) pair -> no race.
__global__ void rope_q_kernel(float* __restrict__ qk,
                              const float* __restrict__ cosT,
                              const float* __restrict__ sinT) {
  int idx = blockIdx.x * blockDim.x + threadIdx.x;  // S * NH * 32
  int s = idx >> 10;
  int rem = idx & 1023;
  int h = rem >> 5, i = rem & 31;
  float c = cosT[(s << 5) + i], sn = sinT[(s << 5) + i];
  float* p = qk + (size_t)s * ETOT + h * HD + i;
  float x1 = p[0], x2 = p[32];
  p[0]  = fmaf(x1, c, -x2 * sn);
  p[32] = fmaf(x2, c,  x1 * sn);
}

// 4) RoPE on k, writing transposed kT[kv][d][s] for coalesced attn loads.
__global__ void rope_k_kernel(const float* __restrict__ qk,
                              float* __restrict__ kT,
                              const float* __restrict__ cosT,
                              const float* __restrict__ sinT) {
  int idx = blockIdx.x * blockDim.x + threadIdx.x;  // S * NKV * 32
  int s = idx & (S - 1);
  int rem = idx >> 11;       // 0..255
  int kv = rem >> 5, i = rem & 31;
  float c = cosT[(s << 5) + i], sn = sinT[(s << 5) + i];
  const float* p = qk + (size_t)s * ETOT + EQ + kv * HD + i;
  float x1 = p[0], x2 = p[32];
  kT[(size_t)(kv * HD + i) * S + s]      = fmaf(x1, c, -x2 * sn);
  kT[(size_t)(kv * HD + i + 32) * S + s] = fmaf(x2, c,  x1 * sn);
}

// ---------------------------------------------------------------------------
// 5) Attention: block = (head, 64 rows) in 4 chunks of 16 rows. Each thread
//    owns 8 CONTIGUOUS columns (float4 loads) of all 2048; one-deep prefetch
//    on the d-loop. Row/col/d accumulation order identical to R1.
__global__ __launch_bounds__(256) void attn_kernel(
    const float* __restrict__ qk, const float* __restrict__ kT,
    float* __restrict__ part) {
  const int h = blockIdx.x;    // 0..31
  const int sb = blockIdx.y;   // 0..31
  const int t = threadIdx.x;
  const float* kTh = kT + (size_t)(h >> 2) * HD * S;
  __shared__ float qlds[16][64];
  __shared__ float wred[4][16];
  float colacc[8];
#pragma unroll
  for (int u = 0; u < 8; ++u) colacc[u] = 0.f;
  const int c0 = t * 8;

  for (int ch = 0; ch < 4; ++ch) {
    const int row0 = sb * 64 + ch * 16;
    __syncthreads();
    {
      const int r = t >> 6, dd = t & 63;
#pragma unroll
      for (int rr = 0; rr < 4; ++rr)
        qlds[r + rr * 4][dd] = qk[(size_t)(row0 + r + rr * 4) * ETOT + h * HD + dd];
    }
    __syncthreads();
    float acc[16][8];
#pragma unroll
    for (int r = 0; r < 16; ++r)
#pragma unroll
      for (int u = 0; u < 8; ++u) acc[r][u] = 0.f;

    float4 ka = *(const float4*)(kTh + c0);
    float4 kb = *(const float4*)(kTh + c0 + 4);
    for (int d = 0; d < HD; ++d) {
      const int dn = (d + 1) & (HD - 1);   // wrap; last prefetch discarded
      const float4 na = *(const float4*)(kTh + (size_t)dn * S + c0);
      const float4 nb = *(const float4*)(kTh + (size_t)dn * S + c0 + 4);
      const float kv[8] = {ka.x, ka.y, ka.z, ka.w, kb.x, kb.y, kb.z, kb.w};
#pragma unroll
      for (int r = 0; r < 16; ++r) {
        const float qd = qlds[r][d];
#pragma unroll
        for (int u = 0; u < 8; ++u) acc[r][u] = fmaf(qd, kv[u], acc[r][u]);
      }
      ka = na; kb = nb;
    }
    // exp + per-row sums (scores tiny: no max-sub needed), deterministic tree
    float p[16];
#pragma unroll
    for (int r = 0; r < 16; ++r) {
      p[r] = 0.f;
#pragma unroll
      for (int u = 0; u < 8; ++u) {
        acc[r][u] = expf(acc[r][u]);
        p[r] += acc[r][u];
      }
    }
#pragma unroll
    for (int off = 32; off > 0; off >>= 1)
#pragma unroll
      for (int r = 0; r < 16; ++r) p[r] += __shfl_xor(p[r], off, 64);
    if ((t & 63) == 0) {
#pragma unroll
      for (int r = 0; r < 16; ++r) wred[t >> 6][r] = p[r];
    }
    __syncthreads();
#pragma unroll
    for (int r = 0; r < 16; ++r) {
      const float Z = wred[0][r] + wred[1][r] + wred[2][r] + wred[3][r];
      const float inv = 1.f / Z;
#pragma unroll
      for (int u = 0; u < 8; ++u) colacc[u] = fmaf(acc[r][u], inv, colacc[u]);
    }
  }
  const int b = h * 32 + sb;
  *(float4*)(part + (size_t)b * S + c0)     = make_float4(colacc[0], colacc[1], colacc[2], colacc[3]);
  *(float4*)(part + (size_t)b * S + c0 + 4) = make_float4(colacc[4], colacc[5], colacc[6], colacc[7]);
}

// ---------------------------------------------------------------------------
// 6) fp64 column totals of the 1024 fp32 partials (single stage, b ascending).
__global__ void vals_kernel(const float* __restrict__ part,
                            double* __restrict__ vals) {
  int j = blockIdx.x * 256 + threadIdx.x;  // 0..2047
  double s = 0.0;
  for (int b = 0; b < 1024; ++b) s += (double)part[(size_t)b * S + j];
  vals[j] = s;
}

// 7) Parallel exact rank -> selection flag (tie-break: lower index wins,
//    matching lax.top_k).
__global__ void flags_kernel(const double* __restrict__ vals,
                             int* __restrict__ flags) {
  int j = blockIdx.x * 256 + threadIdx.x;  // 0..2047
  const double v = vals[j];
  int rank = 0;
  for (int j2 = 0; j2 < S; ++j2) {
    const double v2 = vals[j2];
    rank += (v2 > v) || (v2 == v && j2 < j);
  }
  flags[j] = (rank < KLEN) ? 1 : 0;
}

// 8) Compact selected indices (ascending) + write tokens/indices + append S-1.
__global__ __launch_bounds__(1024) void emit_kernel(
    const int* __restrict__ flags, const int* __restrict__ ids,
    int* __restrict__ out) {
  __shared__ int fl[S];
  __shared__ int csum[32];
  __shared__ int cpre[32];
  const int t = threadIdx.x;
  for (int j = t; j < S; j += 1024) fl[j] = flags[j];
  __syncthreads();
  if (t < 32) {
    int s = 0;
    for (int i = 0; i < 64; ++i) s += fl[t * 64 + i];
    csum[t] = s;
  }
  __syncthreads();
  if (t == 0) {
    int run = 0;
    for (int c = 0; c < 32; ++c) { cpre[c] = run; run += csum[c]; }
  }
  __syncthreads();
  for (int j = t; j < S; j += 1024) {
    if (fl[j]) {
      int pos = cpre[j >> 6];
      for (int j2 = j & ~63; j2 < j; ++j2) pos += fl[j2];
      out[pos] = ids[j];            // pruned tokens [0..1023]
      out[KLEN + 1 + pos] = j;      // indices [1025..2048]
    }
  }
  if (t == 0) {
    out[KLEN] = ids[S - 1];
    out[KLEN + 1 + KLEN] = S - 1;
  }
}

// ---------------------------------------------------------------------------
extern "C" void kernel_launch(void* const* d_in, const int* in_sizes, int n_in,
                              void* d_out, int out_size, void* d_ws, size_t ws_size,
                              hipStream_t stream) {
  const int* ids = (const int*)d_in[0];
  const float* embed = (const float*)d_in[1];
  const float* Wq = (const float*)d_in[2];
  const float* Wk = (const float*)d_in[3];
  int* out = (int*)d_out;
  char* ws = (char*)d_ws;
  float* cosT = (float*)(ws + OFF_COS);
  float* sinT = (float*)(ws + OFF_SIN);
  float* qk   = (float*)(ws + OFF_QK);
  float* kT   = (float*)(ws + OFF_KT);
  float* part = (float*)(ws + OFF_PART);
  double* vals = (double*)(ws + OFF_VALS);
  int* flags  = (int*)(ws + OFF_FLAGS);

  trig_kernel<<<256, 256, 0, stream>>>(cosT, sinT);
  proj_gemm<<<dim3(ETOT / BN, S / BM), 256, 0, stream>>>(ids, embed, Wq, Wk, qk);
  rope_q_kernel<<<(S * NH * 32) / 256, 256, 0, stream>>>(qk, cosT, sinT);
  rope_k_kernel<<<(S * NKV * 32) / 256, 256, 0, stream>>>(qk, kT, cosT, sinT);
  attn_kernel<<<dim3(NH, 32), 256, 0, stream>>>(qk, kT, part);
  vals_kernel<<<S / 256, 256, 0, stream>>>(part, vals);
  flags_kernel<<<S / 256, 256, 0, stream>>>(vals, flags);
  emit_kernel<<<1, 1024, 0, stream>>>(flags, ids, out);
}